// Round 4
// baseline (441.657 us; speedup 1.0000x reference)
//
#include <hip/hip_runtime.h>

// SSIM (16,3,512,512) f32. Fused separable 11x11 Gaussian + SSIM + mean.
// R3: LDS-issue-bound model. Register-blocked passes written with ONLY named
// scalars + literal-index macros (no runtime-indexable arrays -> no scratch).
// h-pass: 2 cols/thread via 12 float2 b64 reads. v-pass: 4 rows/thread via
// 14 x (b64+b64+b32) reads. All LDS phases conflict-free by construction.

#define KSZ   11
#define PAD   5
#define TILE  32
#define HALO  42               // TILE + KSZ - 1
#define SXW   44               // sx row stride in float2
#define NT    256
#define NBX   16
#define NBY   16
#define NPLANES 48
#define NBLOCKS (NBX * NBY * NPLANES)

struct W11 { float w[KSZ]; };

static __device__ __forceinline__ float fast_rcp(float x) {
#if __has_builtin(__builtin_amdgcn_rcpf)
    return __builtin_amdgcn_rcpf(x);
#else
    return 1.0f / x;
#endif
}

__global__ __launch_bounds__(NT)
void ssim_fused(const float* __restrict__ img1,
                const float* __restrict__ img2,
                const float* __restrict__ window,
                double* __restrict__ acc,
                unsigned int* __restrict__ counter,
                float* __restrict__ out)
{
    __shared__ float k1d[KSZ];
    __shared__ __align__(16) float2 sx[HALO * SXW];   // (x1,x2) interleaved
    __shared__ __align__(16) float2 hA[HALO * TILE];  // (h0,h1)
    __shared__ __align__(16) float2 hC[HALO * TILE];  // (h2,h3)
    __shared__ __align__(16) float  hD[HALO * TILE];  // h4
    __shared__ float red[NT / 64];

    const int tid = threadIdx.x;
    const int bx = blockIdx.x * TILE;
    const int by = blockIdx.y * TILE;
    const size_t planeOff = (size_t)blockIdx.z * 512 * 512;
    const float* p1 = img1 + planeOff;
    const float* p2 = img2 + planeOff;

    // 1D kernel = row sums of the 2D window (window = outer(k,k), sum(k)=1).
    if (tid < KSZ) {
        float s = 0.f;
        #pragma unroll
        for (int j = 0; j < KSZ; ++j) s += window[tid * KSZ + j];
        k1d[tid] = s;
    }

    // Stage halo tile (zero outside image = zero padding), b64 LDS writes.
    for (int idx = tid; idx < HALO * HALO; idx += NT) {
        const int r = idx / HALO;
        const int c = idx - r * HALO;
        const int gr = by + r - PAD;
        const int gc = bx + c - PAD;
        float v1 = 0.f, v2 = 0.f;
        if (((unsigned)gr < 512u) && ((unsigned)gc < 512u)) {
            const size_t g = (size_t)gr * 512 + gc;
            v1 = p1[g];
            v2 = p2[g];
        }
        sx[r * SXW + c] = make_float2(v1, v2);
    }
    __syncthreads();

    W11 wk;
    #pragma unroll
    for (int k = 0; k < KSZ; ++k) wk.w[k] = k1d[k];   // constant indices only

    // ---- Horizontal pass: slot = (row r, col-group g) -> output cols 2g,2g+1.
    for (int s = tid; s < HALO * 16; s += NT) {
        const int r  = s >> 4;
        const int g  = s & 15;
        const int c0 = g * 2;
        const float2* row = sx + r * SXW + c0;
        const float2 x0 = row[0],  x1 = row[1],  x2 = row[2],  x3 = row[3];
        const float2 x4 = row[4],  x5 = row[5],  x6 = row[6],  x7 = row[7];
        const float2 x8 = row[8],  x9 = row[9],  x10 = row[10], x11 = row[11];

        float2 m0 = make_float2(0.f, 0.f), m1 = make_float2(0.f, 0.f);
        float2 e0 = make_float2(0.f, 0.f), e1 = make_float2(0.f, 0.f);
        float  d0 = 0.f, d1 = 0.f;

#define HTAP(K, A, B)                                                   \
        {                                                               \
            const float w = wk.w[K];                                    \
            m0.x += w * (A).x;       m0.y += w * (A).y;                 \
            e0.x += w * (A).x*(A).x; e0.y += w * (A).y*(A).y;           \
            d0   += w * (A).x*(A).y;                                    \
            m1.x += w * (B).x;       m1.y += w * (B).y;                 \
            e1.x += w * (B).x*(B).x; e1.y += w * (B).y*(B).y;           \
            d1   += w * (B).x*(B).y;                                    \
        }
        HTAP(0,  x0,  x1)  HTAP(1,  x1,  x2)  HTAP(2,  x2,  x3)
        HTAP(3,  x3,  x4)  HTAP(4,  x4,  x5)  HTAP(5,  x5,  x6)
        HTAP(6,  x6,  x7)  HTAP(7,  x7,  x8)  HTAP(8,  x8,  x9)
        HTAP(9,  x9,  x10) HTAP(10, x10, x11)
#undef HTAP

        const int base = r * TILE + c0;
        *(float4*)(&hA[base]) = make_float4(m0.x, m0.y, m1.x, m1.y);
        *(float4*)(&hC[base]) = make_float4(e0.x, e0.y, e1.x, e1.y);
        *(float2*)(&hD[base]) = make_float2(d0, d1);
    }
    __syncthreads();

    // ---- Vertical pass: thread = (col vc, 4-row group vr0). Named accums.
    const float C1f = 1e-4f;
    const float C2f = 9e-4f;
    float lsum = 0.f;
    {
        const int vc  = tid & 31;
        const int vr0 = (tid >> 5) * 4;

        float2 mu0 = make_float2(0.f,0.f), mu1 = make_float2(0.f,0.f),
               mu2 = make_float2(0.f,0.f), mu3 = make_float2(0.f,0.f);
        float2 ee0 = make_float2(0.f,0.f), ee1 = make_float2(0.f,0.f),
               ee2 = make_float2(0.f,0.f), ee3 = make_float2(0.f,0.f);
        float  dd0 = 0.f, dd1 = 0.f, dd2 = 0.f, dd3 = 0.f;

#define VTAP(J, I, MU, EE, DD)                                          \
        if ((J) >= (I) && (J) - (I) < KSZ) {                            \
            const float w = wk.w[((J) >= (I)) ? (J) - (I) : 0];         \
            MU.x += w * a.x; MU.y += w * a.y;                           \
            EE.x += w * c.x; EE.y += w * c.y;                           \
            DD   += w * d;                                              \
        }
#define VROW(J)                                                         \
        {                                                               \
            const int hr = vr0 + (J);                                   \
            const float2 a = hA[hr * TILE + vc];                        \
            const float2 c = hC[hr * TILE + vc];                        \
            const float  d = hD[hr * TILE + vc];                        \
            VTAP(J, 0, mu0, ee0, dd0)                                   \
            VTAP(J, 1, mu1, ee1, dd1)                                   \
            VTAP(J, 2, mu2, ee2, dd2)                                   \
            VTAP(J, 3, mu3, ee3, dd3)                                   \
        }
        VROW(0)  VROW(1)  VROW(2)  VROW(3)  VROW(4)  VROW(5)  VROW(6)
        VROW(7)  VROW(8)  VROW(9)  VROW(10) VROW(11) VROW(12) VROW(13)
#undef VROW
#undef VTAP

#define SSIMI(MU, EE, DD)                                               \
        {                                                               \
            const float mu1v = MU.x, mu2v = MU.y;                       \
            const float mu1sq = mu1v * mu1v;                            \
            const float mu2sq = mu2v * mu2v;                            \
            const float mu12  = mu1v * mu2v;                            \
            const float s11 = EE.x - mu1sq;                             \
            const float s22 = EE.y - mu2sq;                             \
            const float s12 = DD   - mu12;                              \
            const float num = (2.f * mu12 + C1f) * (2.f * s12 + C2f);   \
            const float den = (mu1sq + mu2sq + C1f) * (s11 + s22 + C2f);\
            lsum += num * fast_rcp(den);                                \
        }
        SSIMI(mu0, ee0, dd0)
        SSIMI(mu1, ee1, dd1)
        SSIMI(mu2, ee2, dd2)
        SSIMI(mu3, ee3, dd3)
#undef SSIMI
    }

    // ---- Block reduction -> one device atomic; last block finalizes.
    #pragma unroll
    for (int off = 32; off > 0; off >>= 1)
        lsum += __shfl_down(lsum, off, 64);
    const int wave = tid >> 6;
    const int lane = tid & 63;
    if (lane == 0) red[wave] = lsum;
    __syncthreads();
    if (tid == 0) {
        const float bsum = red[0] + red[1] + red[2] + red[3];
        atomicAdd(acc, (double)bsum);
        __threadfence();
        const unsigned prev = atomicAdd(counter, 1u);
        if (prev == (unsigned)(NBLOCKS - 1)) {
            __threadfence();
            const double total = atomicAdd(acc, 0.0);
            out[0] = (float)(total * (1.0 / ((double)NBLOCKS * TILE * TILE)));
        }
    }
}

extern "C" void kernel_launch(void* const* d_in, const int* in_sizes, int n_in,
                              void* d_out, int out_size, void* d_ws, size_t ws_size,
                              hipStream_t stream) {
    const float* img1   = (const float*)d_in[0];
    const float* img2   = (const float*)d_in[1];
    const float* window = (const float*)d_in[2];
    float* out = (float*)d_out;
    double* acc = (double*)d_ws;
    unsigned int* counter = (unsigned int*)((char*)d_ws + 8);

    hipMemsetAsync(d_ws, 0, 16, stream);

    dim3 grid(NBX, NBY, NPLANES);
    ssim_fused<<<grid, NT, 0, stream>>>(img1, img2, window, acc, counter, out);
}

// Round 5
// 264.362 us; speedup vs baseline: 1.6707x; 1.6707x over previous
//
#include <hip/hip_runtime.h>

// SSIM (16,3,512,512) f32. Fused separable 11x11 Gaussian + SSIM + mean.
// R5: R3's register-blocked passes UNCHANGED, but NO __threadfence / counter /
// last-block finalize in the main kernel (device-scope fence per block caused
// L2 wb/inv storms on non-coherent per-XCD L2s -> 2x slowdown in R2/R3).
// Reduction: plain global atomicAdd per block; separate finalize kernel.

#define KSZ   11
#define PAD   5
#define TILE  32
#define HALO  42               // TILE + KSZ - 1
#define SXW   44               // sx row stride in float2
#define NT    256
#define NBX   16
#define NBY   16
#define NPLANES 48
#define NBLOCKS (NBX * NBY * NPLANES)

struct W11 { float w[KSZ]; };

static __device__ __forceinline__ float fast_rcp(float x) {
#if __has_builtin(__builtin_amdgcn_rcpf)
    return __builtin_amdgcn_rcpf(x);
#else
    return 1.0f / x;
#endif
}

__global__ __launch_bounds__(NT)
void ssim_fused(const float* __restrict__ img1,
                const float* __restrict__ img2,
                const float* __restrict__ window,
                double* __restrict__ acc)
{
    __shared__ float k1d[KSZ];
    __shared__ __align__(16) float2 sx[HALO * SXW];   // (x1,x2) interleaved
    __shared__ __align__(16) float2 hA[HALO * TILE];  // (h0,h1)
    __shared__ __align__(16) float2 hC[HALO * TILE];  // (h2,h3)
    __shared__ __align__(16) float  hD[HALO * TILE];  // h4
    __shared__ float red[NT / 64];

    const int tid = threadIdx.x;
    const int bx = blockIdx.x * TILE;
    const int by = blockIdx.y * TILE;
    const size_t planeOff = (size_t)blockIdx.z * 512 * 512;
    const float* p1 = img1 + planeOff;
    const float* p2 = img2 + planeOff;

    // 1D kernel = row sums of the 2D window (window = outer(k,k), sum(k)=1).
    if (tid < KSZ) {
        float s = 0.f;
        #pragma unroll
        for (int j = 0; j < KSZ; ++j) s += window[tid * KSZ + j];
        k1d[tid] = s;
    }

    // Stage halo tile (zero outside image = zero padding), b64 LDS writes.
    for (int idx = tid; idx < HALO * HALO; idx += NT) {
        const int r = idx / HALO;
        const int c = idx - r * HALO;
        const int gr = by + r - PAD;
        const int gc = bx + c - PAD;
        float v1 = 0.f, v2 = 0.f;
        if (((unsigned)gr < 512u) && ((unsigned)gc < 512u)) {
            const size_t g = (size_t)gr * 512 + gc;
            v1 = p1[g];
            v2 = p2[g];
        }
        sx[r * SXW + c] = make_float2(v1, v2);
    }
    __syncthreads();

    W11 wk;
    #pragma unroll
    for (int k = 0; k < KSZ; ++k) wk.w[k] = k1d[k];   // constant indices only

    // ---- Horizontal pass: slot = (row r, col-group g) -> output cols 2g,2g+1.
    for (int s = tid; s < HALO * 16; s += NT) {
        const int r  = s >> 4;
        const int g  = s & 15;
        const int c0 = g * 2;
        const float2* row = sx + r * SXW + c0;
        const float2 x0 = row[0],  x1 = row[1],  x2 = row[2],  x3 = row[3];
        const float2 x4 = row[4],  x5 = row[5],  x6 = row[6],  x7 = row[7];
        const float2 x8 = row[8],  x9 = row[9],  x10 = row[10], x11 = row[11];

        float2 m0 = make_float2(0.f, 0.f), m1 = make_float2(0.f, 0.f);
        float2 e0 = make_float2(0.f, 0.f), e1 = make_float2(0.f, 0.f);
        float  d0 = 0.f, d1 = 0.f;

#define HTAP(K, A, B)                                                   \
        {                                                               \
            const float w = wk.w[K];                                    \
            m0.x += w * (A).x;       m0.y += w * (A).y;                 \
            e0.x += w * (A).x*(A).x; e0.y += w * (A).y*(A).y;           \
            d0   += w * (A).x*(A).y;                                    \
            m1.x += w * (B).x;       m1.y += w * (B).y;                 \
            e1.x += w * (B).x*(B).x; e1.y += w * (B).y*(B).y;           \
            d1   += w * (B).x*(B).y;                                    \
        }
        HTAP(0,  x0,  x1)  HTAP(1,  x1,  x2)  HTAP(2,  x2,  x3)
        HTAP(3,  x3,  x4)  HTAP(4,  x4,  x5)  HTAP(5,  x5,  x6)
        HTAP(6,  x6,  x7)  HTAP(7,  x7,  x8)  HTAP(8,  x8,  x9)
        HTAP(9,  x9,  x10) HTAP(10, x10, x11)
#undef HTAP

        const int base = r * TILE + c0;
        *(float4*)(&hA[base]) = make_float4(m0.x, m0.y, m1.x, m1.y);
        *(float4*)(&hC[base]) = make_float4(e0.x, e0.y, e1.x, e1.y);
        *(float2*)(&hD[base]) = make_float2(d0, d1);
    }
    __syncthreads();

    // ---- Vertical pass: thread = (col vc, 4-row group vr0). Named accums.
    const float C1f = 1e-4f;
    const float C2f = 9e-4f;
    float lsum = 0.f;
    {
        const int vc  = tid & 31;
        const int vr0 = (tid >> 5) * 4;

        float2 mu0 = make_float2(0.f,0.f), mu1 = make_float2(0.f,0.f),
               mu2 = make_float2(0.f,0.f), mu3 = make_float2(0.f,0.f);
        float2 ee0 = make_float2(0.f,0.f), ee1 = make_float2(0.f,0.f),
               ee2 = make_float2(0.f,0.f), ee3 = make_float2(0.f,0.f);
        float  dd0 = 0.f, dd1 = 0.f, dd2 = 0.f, dd3 = 0.f;

#define VTAP(J, I, MU, EE, DD)                                          \
        if ((J) >= (I) && (J) - (I) < KSZ) {                            \
            const float w = wk.w[((J) >= (I)) ? (J) - (I) : 0];         \
            MU.x += w * a.x; MU.y += w * a.y;                           \
            EE.x += w * c.x; EE.y += w * c.y;                           \
            DD   += w * d;                                              \
        }
#define VROW(J)                                                         \
        {                                                               \
            const int hr = vr0 + (J);                                   \
            const float2 a = hA[hr * TILE + vc];                        \
            const float2 c = hC[hr * TILE + vc];                        \
            const float  d = hD[hr * TILE + vc];                        \
            VTAP(J, 0, mu0, ee0, dd0)                                   \
            VTAP(J, 1, mu1, ee1, dd1)                                   \
            VTAP(J, 2, mu2, ee2, dd2)                                   \
            VTAP(J, 3, mu3, ee3, dd3)                                   \
        }
        VROW(0)  VROW(1)  VROW(2)  VROW(3)  VROW(4)  VROW(5)  VROW(6)
        VROW(7)  VROW(8)  VROW(9)  VROW(10) VROW(11) VROW(12) VROW(13)
#undef VROW
#undef VTAP

#define SSIMI(MU, EE, DD)                                               \
        {                                                               \
            const float mu1v = MU.x, mu2v = MU.y;                       \
            const float mu1sq = mu1v * mu1v;                            \
            const float mu2sq = mu2v * mu2v;                            \
            const float mu12  = mu1v * mu2v;                            \
            const float s11 = EE.x - mu1sq;                             \
            const float s22 = EE.y - mu2sq;                             \
            const float s12 = DD   - mu12;                              \
            const float num = (2.f * mu12 + C1f) * (2.f * s12 + C2f);   \
            const float den = (mu1sq + mu2sq + C1f) * (s11 + s22 + C2f);\
            lsum += num * fast_rcp(den);                                \
        }
        SSIMI(mu0, ee0, dd0)
        SSIMI(mu1, ee1, dd1)
        SSIMI(mu2, ee2, dd2)
        SSIMI(mu3, ee3, dd3)
#undef SSIMI
    }

    // ---- Block reduction -> ONE device-scope atomic per block. No fence.
    #pragma unroll
    for (int off = 32; off > 0; off >>= 1)
        lsum += __shfl_down(lsum, off, 64);
    const int wave = tid >> 6;
    const int lane = tid & 63;
    if (lane == 0) red[wave] = lsum;
    __syncthreads();
    if (tid == 0) {
        const float bsum = red[0] + red[1] + red[2] + red[3];
        atomicAdd(acc, (double)bsum);
    }
}

__global__ __launch_bounds__(64)
void ssim_finalize(const double* __restrict__ acc, float* __restrict__ out) {
    if (threadIdx.x == 0)
        out[0] = (float)(acc[0] * (1.0 / ((double)NBLOCKS * TILE * TILE)));
}

extern "C" void kernel_launch(void* const* d_in, const int* in_sizes, int n_in,
                              void* d_out, int out_size, void* d_ws, size_t ws_size,
                              hipStream_t stream) {
    const float* img1   = (const float*)d_in[0];
    const float* img2   = (const float*)d_in[1];
    const float* window = (const float*)d_in[2];
    float* out = (float*)d_out;
    double* acc = (double*)d_ws;

    hipMemsetAsync(d_ws, 0, 8, stream);

    dim3 grid(NBX, NBY, NPLANES);
    ssim_fused<<<grid, NT, 0, stream>>>(img1, img2, window, acc);
    ssim_finalize<<<1, 64, 0, stream>>>(acc, out);
}